// Round 1
// baseline (2785.466 us; speedup 1.0000x reference)
//
#include <hip/hip_runtime.h>
#include <math.h>

#define KK 5
#define KD 125
#define NUM_GRAPHS 64

// ---------------- Conv A scatter: s_acc[dst][idx] += w * x[src], deg[dst]++ ----------------
__global__ void scatter_a(const float* __restrict__ x, const float* __restrict__ pseudo,
                          const int* __restrict__ ei, int E,
                          float* __restrict__ sacc, float* __restrict__ deg) {
    int e = blockIdx.x * blockDim.x + threadIdx.x;
    if (e >= E) return;
    int src = ei[e], dst = ei[E + e];
    float fr[3]; int k0[3];
#pragma unroll
    for (int d = 0; d < 3; d++) {
        float v = pseudo[e * 3 + d] * (float)(KK - 1);
        float fl = floorf(v);
        k0[d] = (int)fl;
        fr[d] = v - fl;
    }
    float xs = x[src];
    atomicAdd(&deg[dst], 1.0f);
    float* base = sacc + (size_t)dst * KD;
#pragma unroll
    for (int bits = 0; bits < 8; bits++) {
        float w = 1.0f; int idx = 0;
#pragma unroll
        for (int d = 0; d < 3; d++) {
            int b = (bits >> d) & 1;
            w *= b ? fr[d] : (1.0f - fr[d]);
            idx = idx * KK + k0[d] + b;
        }
        atomicAdd(base + idx, w * xs);
    }
}

// ---------------- Conv A node transform: f1 = relu(sacc @ Wa / deg + x*root + bias) --------
template<int C1>
__global__ void node_a(const float* __restrict__ sacc, const float* __restrict__ x,
                       const float* __restrict__ Wa, const float* __restrict__ root,
                       const float* __restrict__ bias, const float* __restrict__ deg,
                       float* __restrict__ f1) {
    __shared__ float sh[KD];
    int node = blockIdx.x;
    int t = threadIdx.x;  // 64 threads
    for (int k = t; k < KD; k += 64) sh[k] = sacc[(size_t)node * KD + k];
    __syncthreads();
    if (t < C1) {
        float s = 0.f;
#pragma unroll
        for (int k = 0; k < KD; k++) s = fmaf(sh[k], Wa[k * C1 + t], s);
        float d = deg[node]; d = d > 1.f ? d : 1.f;
        float o = s / d + x[node] * root[t] + bias[t];
        f1[(size_t)node * C1 + t] = o > 0.f ? o : 0.f;
    }
}

// ---------------- Conv B: one wave per edge, lane = output channel ----------------
template<int CIN>
__global__ void conv_b(const float* __restrict__ f1, const float* __restrict__ pseudo,
                       const int* __restrict__ ei, int E,
                       const float* __restrict__ Wb, float* __restrict__ accb) {
    int lane = threadIdx.x & 63;
    int e = blockIdx.x * (blockDim.x >> 6) + (threadIdx.x >> 6);
    if (e >= E) return;
    int src = ei[e], dst = ei[E + e];
    float fr[3]; int k0[3];
#pragma unroll
    for (int d = 0; d < 3; d++) {
        float v = pseudo[e * 3 + d] * (float)(KK - 1);
        float fl = floorf(v);
        k0[d] = (int)fl;
        fr[d] = v - fl;
    }
    float w[8]; int idx[8];
#pragma unroll
    for (int bits = 0; bits < 8; bits++) {
        float ww = 1.f; int ii = 0;
#pragma unroll
        for (int d = 0; d < 3; d++) {
            int b = (bits >> d) & 1;
            ww *= b ? fr[d] : (1.f - fr[d]);
            ii = ii * KK + k0[d] + b;
        }
        w[bits] = ww; idx[bits] = ii;
    }
    float freg = (lane < CIN) ? f1[(size_t)src * CIN + lane] : 0.f;
    const float* bp[8];
#pragma unroll
    for (int c = 0; c < 8; c++) bp[c] = Wb + (size_t)idx[c] * CIN * 64 + lane;
    float p[8];
#pragma unroll
    for (int c = 0; c < 8; c++) p[c] = 0.f;
#pragma unroll 4
    for (int i = 0; i < CIN; i++) {
        float fi = __shfl(freg, i, 64);
#pragma unroll
        for (int c = 0; c < 8; c++) {
            p[c] = fmaf(fi, bp[c][i * 64], p[c]);
        }
    }
    float acc = 0.f;
#pragma unroll
    for (int c = 0; c < 8; c++) acc = fmaf(w[c], p[c], acc);
    atomicAdd(&accb[(size_t)dst * 64 + lane], acc);
}

// ---------------- Conv B node epilogue + fused graph readout ----------------
template<int CIN>
__global__ void node_b(const float* __restrict__ accb, const float* __restrict__ f1,
                       const float* __restrict__ rootb, const float* __restrict__ biasb,
                       const float* __restrict__ deg, const int* __restrict__ batch,
                       float* __restrict__ hsum, float* __restrict__ gcnt, int lvloff) {
    __shared__ float sh[CIN];
    int node = blockIdx.x;
    int t = threadIdx.x;  // 64 threads
    if (t < CIN) sh[t] = f1[(size_t)node * CIN + t];
    __syncthreads();
    float s = accb[(size_t)node * 64 + t];
    float d = deg[node]; d = d > 1.f ? d : 1.f;
    s /= d;
#pragma unroll
    for (int i = 0; i < CIN; i++) s = fmaf(sh[i], rootb[i * 64 + t], s);
    s += biasb[t];
    s = s > 0.f ? s : 0.f;
    int g = batch[node];
    atomicAdd(&hsum[g * 320 + lvloff + t], s);
    if (t == 0) atomicAdd(&gcnt[g], 1.0f);
}

// ---------------- FC + log_softmax: one thread per graph ----------------
__global__ void fc_kernel(const float* __restrict__ hsum, const float* __restrict__ gcnt,
                          const float* __restrict__ fcw, const float* __restrict__ fcb,
                          float* __restrict__ out) {
    int g = threadIdx.x;
    if (g >= NUM_GRAPHS) return;
    float logit[10];
#pragma unroll
    for (int t = 0; t < 10; t++) logit[t] = fcb[t];
    for (int j = 0; j < 320; j++) {
        float c = gcnt[(j >> 6) * NUM_GRAPHS + g];
        c = c > 1.f ? c : 1.f;
        float h = hsum[g * 320 + j] / c;
#pragma unroll
        for (int t = 0; t < 10; t++) logit[t] = fmaf(h, fcw[j * 10 + t], logit[t]);
    }
    float m = logit[0];
#pragma unroll
    for (int t = 1; t < 10; t++) m = fmaxf(m, logit[t]);
    float sum = 0.f;
#pragma unroll
    for (int t = 0; t < 10; t++) sum += expf(logit[t] - m);
    float lse = m + logf(sum);
#pragma unroll
    for (int t = 0; t < 10; t++) out[g * 10 + t] = logit[t] - lse;
}

extern "C" void kernel_launch(void* const* d_in, const int* in_sizes, int n_in,
                              void* d_out, int out_size, void* d_ws, size_t ws_size,
                              hipStream_t stream) {
    static const int Ns[5] = {20000, 10000, 5000, 2500, 1250};
    static const int Es[5] = {320000, 160000, 80000, 40000, 20000};

    float* ws   = (float*)d_ws;
    float* deg  = ws;                       // 20000
    float* sacc = deg + 20000;              // 20000*125
    float* f1   = sacc + 20000 * KD;        // 20000*64
    float* accb = f1 + 20000 * 64;          // 20000*64
    float* hsum = accb + 20000 * 64;        // 64*320
    float* gcnt = hsum + NUM_GRAPHS * 320;  // 5*64

    // zero global-readout accumulators once (hsum and gcnt are contiguous)
    hipMemsetAsync(hsum, 0, (NUM_GRAPHS * 320 + 5 * NUM_GRAPHS) * sizeof(float), stream);

    for (int l = 0; l < 5; l++) {
        const int b = l * 10;
        const float* x      = (const float*)d_in[b + 0];
        const float* pseudo = (const float*)d_in[b + 1];
        const int*   ei     = (const int*)d_in[b + 2];
        const int*   batch  = (const int*)d_in[b + 3];
        const float* Wa     = (const float*)d_in[b + 4];
        const float* roota  = (const float*)d_in[b + 5];
        const float* biasa  = (const float*)d_in[b + 6];
        const float* Wb     = (const float*)d_in[b + 7];
        const float* rootb  = (const float*)d_in[b + 8];
        const float* biasb  = (const float*)d_in[b + 9];
        int n = Ns[l], e = Es[l];

        hipMemsetAsync(deg, 0, n * sizeof(float), stream);
        hipMemsetAsync(sacc, 0, (size_t)n * KD * sizeof(float), stream);
        hipMemsetAsync(accb, 0, (size_t)n * 64 * sizeof(float), stream);

        scatter_a<<<(e + 255) / 256, 256, 0, stream>>>(x, pseudo, ei, e, sacc, deg);
        if (l == 0) {
            node_a<32><<<n, 64, 0, stream>>>(sacc, x, Wa, roota, biasa, deg, f1);
            conv_b<32><<<(e + 3) / 4, 256, 0, stream>>>(f1, pseudo, ei, e, Wb, accb);
            node_b<32><<<n, 64, 0, stream>>>(accb, f1, rootb, biasb, deg, batch,
                                             hsum, gcnt + l * NUM_GRAPHS, l * 64);
        } else {
            node_a<64><<<n, 64, 0, stream>>>(sacc, x, Wa, roota, biasa, deg, f1);
            conv_b<64><<<(e + 3) / 4, 256, 0, stream>>>(f1, pseudo, ei, e, Wb, accb);
            node_b<64><<<n, 64, 0, stream>>>(accb, f1, rootb, biasb, deg, batch,
                                             hsum, gcnt + l * NUM_GRAPHS, l * 64);
        }
    }

    const float* fcw = (const float*)d_in[50];
    const float* fcb = (const float*)d_in[51];
    fc_kernel<<<1, 64, 0, stream>>>(hsum, gcnt, fcw, fcb, (float*)d_out);
}

// Round 2
// 2397.907 us; speedup vs baseline: 1.1616x; 1.1616x over previous
//
#include <hip/hip_runtime.h>
#include <math.h>

#define KK 5
#define NUM_GRAPHS 64
#define MAXN 20000
#define MAXE 320000

__device__ __forceinline__ int rfl(int v) { return __builtin_amdgcn_readfirstlane(v); }

// ---------------- Sort stage 1: per-block cell histogram + degree count ----------------
__global__ void sort_hist(const float* __restrict__ pseudo, const int* __restrict__ ei,
                          int E, int* __restrict__ bb, float* __restrict__ deg) {
    __shared__ int h[64];
    int t = threadIdx.x;
    if (t < 64) h[t] = 0;
    __syncthreads();
    int e = blockIdx.x * 256 + t;
    if (e < E) {
        atomicAdd(&deg[ei[E + e]], 1.0f);
        int k0 = (int)floorf(pseudo[e * 3 + 0] * 4.f);
        int k1 = (int)floorf(pseudo[e * 3 + 1] * 4.f);
        int k2 = (int)floorf(pseudo[e * 3 + 2] * 4.f);
        atomicAdd(&h[k0 * 16 + k1 * 4 + k2], 1);
    }
    __syncthreads();
    if (t < 64) bb[blockIdx.x * 64 + t] = h[t];
}

// ---------------- Sort stage 2: scan block counts per cell + cell bases (1 wave) --------
__global__ void sort_scan(int* __restrict__ bb, int nblk, int* __restrict__ cs) {
    int c = threadIdx.x;  // 64 threads, lane = cell
    int run = 0;
    int b = 0;
    for (; b + 8 <= nblk; b += 8) {
        int v[8];
#pragma unroll
        for (int u = 0; u < 8; u++) v[u] = bb[(b + u) * 64 + c];
#pragma unroll
        for (int u = 0; u < 8; u++) { bb[(b + u) * 64 + c] = run; run += v[u]; }
    }
    for (; b < nblk; b++) { int v = bb[b * 64 + c]; bb[b * 64 + c] = run; run += v; }
    int total = run, x = total;
#pragma unroll
    for (int off = 1; off < 64; off <<= 1) { int y = __shfl_up(x, off, 64); if (c >= off) x += y; }
    cs[c] = x - total;  // exclusive scan across cells
}

// ---------------- Sort stage 3: scatter edges into cell-sorted arrays ----------------
__global__ void sort_scatter(const float* __restrict__ pseudo, const int* __restrict__ ei,
                             int E, const int* __restrict__ bb, const int* __restrict__ cs,
                             int* __restrict__ ssrc, int* __restrict__ sdst, int* __restrict__ scell,
                             float* __restrict__ sfx, float* __restrict__ sfy, float* __restrict__ sfz) {
    __shared__ int base[64];
    __shared__ int cnt[64];
    int t = threadIdx.x;
    if (t < 64) { base[t] = bb[blockIdx.x * 64 + t] + cs[t]; cnt[t] = 0; }
    __syncthreads();
    int e = blockIdx.x * 256 + t;
    if (e < E) {
        float v0 = pseudo[e * 3 + 0] * 4.f, v1 = pseudo[e * 3 + 1] * 4.f, v2 = pseudo[e * 3 + 2] * 4.f;
        float f0 = floorf(v0), f1f = floorf(v1), f2 = floorf(v2);
        int c = (int)f0 * 16 + (int)f1f * 4 + (int)f2;
        int r = atomicAdd(&cnt[c], 1);
        int pos = base[c] + r;
        ssrc[pos] = ei[e];
        sdst[pos] = ei[E + e];
        scell[pos] = c;
        sfx[pos] = v0 - f0; sfy[pos] = v1 - f1f; sfz[pos] = v2 - f2;
    }
}

// ---------------- Conv A (cin=1): wave walks sorted edges, 8 w-regs per cell ----------
template<int C1>
__launch_bounds__(256)
__global__ void conv_a(const float* __restrict__ x, const int* __restrict__ ssrc,
                       const int* __restrict__ sdst, const int* __restrict__ scell,
                       const float* __restrict__ sfx, const float* __restrict__ sfy,
                       const float* __restrict__ sfz,
                       const float* __restrict__ Wa, int E, float* __restrict__ f1) {
    const int EPW = 64;
    int lane = threadIdx.x & 63;
    int wid = rfl((int)(threadIdx.x >> 6));
    int base = (blockIdx.x * 4 + wid) * EPW;
    int cur = -1;
    float wv[8];
    for (int j = 0; j < EPW; j++) {
        int e = base + j;
        if (e >= E) break;
        int cell = rfl(scell[e]);
        if (cell != cur) {
            cur = cell;
            int k0x = cell >> 4, k0y = (cell >> 2) & 3, k0z = cell & 3;
#pragma unroll
            for (int cor = 0; cor < 8; cor++) {
                int slot = (k0x + (cor & 1)) * 25 + (k0y + ((cor >> 1) & 1)) * 5 + (k0z + ((cor >> 2) & 1));
                wv[cor] = (lane < C1) ? Wa[slot * C1 + lane] : 0.f;
            }
        }
        float fx = sfx[e], fy = sfy[e], fz = sfz[e];
        float gx = 1.f - fx, gy = 1.f - fy, gz = 1.f - fz;
        float p = 0.f;
#pragma unroll
        for (int cor = 0; cor < 8; cor++) {
            float wc = ((cor & 1) ? fx : gx) * (((cor >> 1) & 1) ? fy : gy) * (((cor >> 2) & 1) ? fz : gz);
            p = fmaf(wc, wv[cor], p);
        }
        float xs = x[rfl(ssrc[e])];
        if (lane < C1) atomicAdd(&f1[(size_t)rfl(sdst[e]) * C1 + lane], xs * p);
    }
}

// ---------------- Conv A epilogue: f1 = relu(f1/deg + x*root + bias) ----------------
template<int C1>
__global__ void node_a2(float* __restrict__ f1, const float* __restrict__ x,
                        const float* __restrict__ root, const float* __restrict__ bias,
                        const float* __restrict__ deg, int n) {
    int i = blockIdx.x * blockDim.x + threadIdx.x;
    if (i >= n * C1) return;
    int node = i / C1, ch = i - node * C1;
    float d = fmaxf(deg[node], 1.f);
    float o = f1[i] / d + x[node] * root[ch] + bias[ch];
    f1[i] = fmaxf(o, 0.f);
}

// ---------------- Conv B: wave walks sorted edges, W column in VGPRs ----------------
template<int CIN, int EPW>
__launch_bounds__(256)
__global__ void conv_bk(const float* __restrict__ f1, const int* __restrict__ ssrc,
                        const int* __restrict__ sdst, const int* __restrict__ scell,
                        const float* __restrict__ sfx, const float* __restrict__ sfy,
                        const float* __restrict__ sfz,
                        const float* __restrict__ Wb, int E, float* __restrict__ accb) {
    __shared__ float sacc[4 * EPW * 64];
    int lane = threadIdx.x & 63;
    int wid = rfl((int)(threadIdx.x >> 6));
    int base = (blockIdx.x * 4 + wid) * EPW;
    float* my = sacc + (wid * EPW) * 64 + lane;
#pragma unroll 1
    for (int cor = 0; cor < 8; cor++) {
        int bx = cor & 1, by = (cor >> 1) & 1, bz = (cor >> 2) & 1;
        int cur = -1;
        float w_reg[CIN];
        for (int j = 0; j < EPW; j++) {
            int e = base + j;
            if (e >= E) break;
            int cell = rfl(scell[e]);
            int slot = ((cell >> 4) + bx) * 25 + (((cell >> 2) & 3) + by) * 5 + ((cell & 3) + bz);
            if (slot != cur) {
                cur = slot;
                const float* wp = Wb + (size_t)slot * CIN * 64 + lane;
#pragma unroll
                for (int i = 0; i < CIN; i++) w_reg[i] = wp[i * 64];
            }
            float fx = sfx[e], fy = sfy[e], fz = sfz[e];
            float wc = (bx ? fx : 1.f - fx) * (by ? fy : 1.f - fy) * (bz ? fz : 1.f - fz);
            const float4* f4 = (const float4*)(f1 + (size_t)rfl(ssrc[e]) * CIN);
            float p0 = 0.f, p1 = 0.f, p2 = 0.f, p3 = 0.f;
#pragma unroll
            for (int i = 0; i < CIN / 4; i++) {
                float4 fv = f4[i];
                p0 = fmaf(fv.x, w_reg[4 * i + 0], p0);
                p1 = fmaf(fv.y, w_reg[4 * i + 1], p1);
                p2 = fmaf(fv.z, w_reg[4 * i + 2], p2);
                p3 = fmaf(fv.w, w_reg[4 * i + 3], p3);
            }
            float r = wc * ((p0 + p1) + (p2 + p3));
            float* ap = my + j * 64;
            if (cor == 0) *ap = r; else *ap += r;
        }
    }
    for (int j = 0; j < EPW; j++) {
        int e = base + j;
        if (e >= E) break;
        atomicAdd(&accb[(size_t)rfl(sdst[e]) * 64 + lane], my[j * 64]);
    }
}

// ---------------- Conv B node epilogue + fused graph readout ----------------
template<int CIN>
__global__ void node_b(const float* __restrict__ accb, const float* __restrict__ f1,
                       const float* __restrict__ rootb, const float* __restrict__ biasb,
                       const float* __restrict__ deg, const int* __restrict__ batch,
                       float* __restrict__ hsum, float* __restrict__ gcnt, int lvloff) {
    __shared__ float sh[CIN];
    int node = blockIdx.x;
    int t = threadIdx.x;  // 64 threads
    if (t < CIN) sh[t] = f1[(size_t)node * CIN + t];
    __syncthreads();
    float s = accb[(size_t)node * 64 + t];
    float d = fmaxf(deg[node], 1.f);
    s /= d;
#pragma unroll
    for (int i = 0; i < CIN; i++) s = fmaf(sh[i], rootb[i * 64 + t], s);
    s += biasb[t];
    s = fmaxf(s, 0.f);
    int g = batch[node];
    atomicAdd(&hsum[g * 320 + lvloff + t], s);
    if (t == 0) atomicAdd(&gcnt[g], 1.0f);
}

// ---------------- FC + log_softmax ----------------
__global__ void fc_kernel(const float* __restrict__ hsum, const float* __restrict__ gcnt,
                          const float* __restrict__ fcw, const float* __restrict__ fcb,
                          float* __restrict__ out) {
    int g = threadIdx.x;
    if (g >= NUM_GRAPHS) return;
    float logit[10];
#pragma unroll
    for (int t = 0; t < 10; t++) logit[t] = fcb[t];
    for (int j = 0; j < 320; j++) {
        float c = fmaxf(gcnt[(j >> 6) * NUM_GRAPHS + g], 1.f);
        float h = hsum[g * 320 + j] / c;
#pragma unroll
        for (int t = 0; t < 10; t++) logit[t] = fmaf(h, fcw[j * 10 + t], logit[t]);
    }
    float m = logit[0];
#pragma unroll
    for (int t = 1; t < 10; t++) m = fmaxf(m, logit[t]);
    float sum = 0.f;
#pragma unroll
    for (int t = 0; t < 10; t++) sum += expf(logit[t] - m);
    float lse = m + logf(sum);
#pragma unroll
    for (int t = 0; t < 10; t++) out[g * 10 + t] = logit[t] - lse;
}

extern "C" void kernel_launch(void* const* d_in, const int* in_sizes, int n_in,
                              void* d_out, int out_size, void* d_ws, size_t ws_size,
                              hipStream_t stream) {
    static const int Ns[5] = {20000, 10000, 5000, 2500, 1250};
    static const int Es[5] = {320000, 160000, 80000, 40000, 20000};

    float* ws   = (float*)d_ws;
    float* deg  = ws;                                // 20000
    float* f1   = deg + MAXN;                        // 20000*64
    float* accb = f1 + (size_t)MAXN * 64;            // 20000*64
    int*   ssrc = (int*)(accb + (size_t)MAXN * 64);  // MAXE
    int*   sdst = ssrc + MAXE;
    int*   scell = sdst + MAXE;
    float* sfx  = (float*)(scell + MAXE);
    float* sfy  = sfx + MAXE;
    float* sfz  = sfy + MAXE;
    int*   bb   = (int*)(sfz + MAXE);                // 1250*64
    int*   cs   = bb + 1250 * 64;                    // 64
    float* hsum = (float*)(cs + 64);                 // 64*320
    float* gcnt = hsum + NUM_GRAPHS * 320;           // 5*64

    hipMemsetAsync(hsum, 0, (NUM_GRAPHS * 320 + 5 * NUM_GRAPHS) * sizeof(float), stream);

    for (int l = 0; l < 5; l++) {
        const int b = l * 10;
        const float* x      = (const float*)d_in[b + 0];
        const float* pseudo = (const float*)d_in[b + 1];
        const int*   ei     = (const int*)d_in[b + 2];
        const int*   batch  = (const int*)d_in[b + 3];
        const float* Wa     = (const float*)d_in[b + 4];
        const float* roota  = (const float*)d_in[b + 5];
        const float* biasa  = (const float*)d_in[b + 6];
        const float* Wb     = (const float*)d_in[b + 7];
        const float* rootb  = (const float*)d_in[b + 8];
        const float* biasb  = (const float*)d_in[b + 9];
        int n = Ns[l], e = Es[l];
        int c1 = (l == 0) ? 32 : 64;

        // zero deg + f1-accumulator (contiguous) and accb
        hipMemsetAsync(deg, 0, (MAXN + (size_t)n * c1) * sizeof(float), stream);
        hipMemsetAsync(accb, 0, (size_t)n * 64 * sizeof(float), stream);

        int nblkS = (e + 255) / 256;
        sort_hist<<<nblkS, 256, 0, stream>>>(pseudo, ei, e, bb, deg);
        sort_scan<<<1, 64, 0, stream>>>(bb, nblkS, cs);
        sort_scatter<<<nblkS, 256, 0, stream>>>(pseudo, ei, e, bb, cs,
                                                ssrc, sdst, scell, sfx, sfy, sfz);

        int ga = (e + 4 * 64 - 1) / (4 * 64);
        int gb = (e + 4 * 32 - 1) / (4 * 32);
        if (l == 0) {
            conv_a<32><<<ga, 256, 0, stream>>>(x, ssrc, sdst, scell, sfx, sfy, sfz, Wa, e, f1);
            node_a2<32><<<(n * 32 + 255) / 256, 256, 0, stream>>>(f1, x, roota, biasa, deg, n);
            conv_bk<32, 32><<<gb, 256, 0, stream>>>(f1, ssrc, sdst, scell, sfx, sfy, sfz, Wb, e, accb);
            node_b<32><<<n, 64, 0, stream>>>(accb, f1, rootb, biasb, deg, batch,
                                             hsum, gcnt + l * NUM_GRAPHS, l * 64);
        } else {
            conv_a<64><<<ga, 256, 0, stream>>>(x, ssrc, sdst, scell, sfx, sfy, sfz, Wa, e, f1);
            node_a2<64><<<(n * 64 + 255) / 256, 256, 0, stream>>>(f1, x, roota, biasa, deg, n);
            conv_bk<64, 32><<<gb, 256, 0, stream>>>(f1, ssrc, sdst, scell, sfx, sfy, sfz, Wb, e, accb);
            node_b<64><<<n, 64, 0, stream>>>(accb, f1, rootb, biasb, deg, batch,
                                             hsum, gcnt + l * NUM_GRAPHS, l * 64);
        }
    }

    const float* fcw = (const float*)d_in[50];
    const float* fcb = (const float*)d_in[51];
    fc_kernel<<<1, 64, 0, stream>>>(hsum, gcnt, fcw, fcb, (float*)d_out);
}

// Round 3
// 1024.946 us; speedup vs baseline: 2.7177x; 2.3395x over previous
//
#include <hip/hip_runtime.h>
#include <math.h>

#define KK 5
#define NUM_GRAPHS 64
#define MAXN 20000
#define MAXE 320000
#define MAXTILE1 (MAXE / 64 + 64)

typedef unsigned short ushortT;
typedef __attribute__((ext_vector_type(8))) short bf16x8;
typedef __attribute__((ext_vector_type(4))) float f32x4;

__device__ __forceinline__ int rfl(int v) { return __builtin_amdgcn_readfirstlane(v); }

__device__ __forceinline__ ushortT f2bf(float f) {
    union { float f; unsigned int u; } v; v.f = f;
    unsigned int r = (v.u + 0x7FFFu + ((v.u >> 16) & 1u)) >> 16;
    return (ushortT)r;
}
__device__ __forceinline__ float bf2f(ushortT h) {
    union { float f; unsigned int u; } v; v.u = ((unsigned int)h) << 16;
    return v.f;
}

// ---------------- Sort stage 1: per-block cell histogram + degree count ----------------
__global__ void sort_hist(const float* __restrict__ pseudo, const int* __restrict__ ei,
                          int E, int* __restrict__ bb, float* __restrict__ deg) {
    __shared__ int h[64];
    int t = threadIdx.x;
    if (t < 64) h[t] = 0;
    __syncthreads();
    int e = blockIdx.x * 256 + t;
    if (e < E) {
        atomicAdd(&deg[ei[E + e]], 1.0f);
        int k0 = (int)floorf(pseudo[e * 3 + 0] * 4.f);
        int k1 = (int)floorf(pseudo[e * 3 + 1] * 4.f);
        int k2 = (int)floorf(pseudo[e * 3 + 2] * 4.f);
        atomicAdd(&h[k0 * 16 + k1 * 4 + k2], 1);
    }
    __syncthreads();
    if (t < 64) bb[blockIdx.x * 64 + t] = h[t];
}

// ------- Sort stage 2: per-cell block-offset scan + padded cell bases + tile map -------
__global__ void sort_scan(int* __restrict__ bb, int nblk, int* __restrict__ cs_pad,
                          int* __restrict__ cellTot, int* __restrict__ cellOfTile,
                          int maxTiles) {
    int c = threadIdx.x;  // 64 threads, lane = cell
    int run = 0;
    int b = 0;
    for (; b + 8 <= nblk; b += 8) {
        int v[8];
#pragma unroll
        for (int u = 0; u < 8; u++) v[u] = bb[(b + u) * 64 + c];
#pragma unroll
        for (int u = 0; u < 8; u++) { bb[(b + u) * 64 + c] = run; run += v[u]; }
    }
    for (; b < nblk; b++) { int v = bb[b * 64 + c]; bb[b * 64 + c] = run; run += v; }
    int tot = run;
    cellTot[c] = tot;
    int tiles = (tot + 63) >> 6;
    int x = tiles;
#pragma unroll
    for (int off = 1; off < 64; off <<= 1) { int y = __shfl_up(x, off, 64); if (c >= off) x += y; }
    int tileBase = x - tiles;  // exclusive scan of tile counts
    cs_pad[c] = tileBase * 64;
    for (int i = 0; i < tiles; i++) cellOfTile[tileBase + i] = c;
    int nT = __shfl(x, 63, 64);
    for (int i = nT + c; i < maxTiles; i += 64) cellOfTile[i] = -1;
}

// ---------------- Sort stage 3: scatter edges into padded cell-sorted arrays ----------
__global__ void sort_scatter(const float* __restrict__ pseudo, const int* __restrict__ ei,
                             int E, const int* __restrict__ bb, const int* __restrict__ cs_pad,
                             int* __restrict__ ssrc, int* __restrict__ sdst,
                             float* __restrict__ sfx, float* __restrict__ sfy, float* __restrict__ sfz) {
    __shared__ int base[64];
    __shared__ int cnt[64];
    int t = threadIdx.x;
    if (t < 64) { base[t] = bb[blockIdx.x * 64 + t] + cs_pad[t]; cnt[t] = 0; }
    __syncthreads();
    int e = blockIdx.x * 256 + t;
    if (e < E) {
        float v0 = pseudo[e * 3 + 0] * 4.f, v1 = pseudo[e * 3 + 1] * 4.f, v2 = pseudo[e * 3 + 2] * 4.f;
        float f0 = floorf(v0), f1f = floorf(v1), f2 = floorf(v2);
        int c = (int)f0 * 16 + (int)f1f * 4 + (int)f2;
        int r = atomicAdd(&cnt[c], 1);
        int pos = base[c] + r;
        ssrc[pos] = ei[e];
        sdst[pos] = ei[E + e];
        sfx[pos] = v0 - f0; sfy[pos] = v1 - f1f; sfz[pos] = v2 - f2;
    }
}

// -------- W swizzle: Wb[125][CIN][64] fp32 -> MFMA B-frag-ordered bf16 hi/lo ----------
// layout: frag (slot, kstep, nblk): 64 lanes x uint4 (8 bf16: k = kstep*32 + (lane>>4)*8 + j,
//         n = nblk*16 + (lane&15))
template<int CIN>
__global__ void wswz(const float* __restrict__ Wb, uint4* __restrict__ hi4, uint4* __restrict__ lo4) {
    const int T = CIN / 32;
    int idx = blockIdx.x * 256 + threadIdx.x;
    if (idx >= 125 * T * 4 * 64) return;
    int lane = idx & 63;
    int blk = (idx >> 6) & 3;
    int rest = idx >> 8;            // s*T + st
    int st = rest % T;
    int s = rest / T;
    int q = lane >> 4, n = blk * 16 + (lane & 15);
    ushortT h[8], l[8];
#pragma unroll
    for (int j = 0; j < 8; j++) {
        int k = st * 32 + q * 8 + j;
        float wv = Wb[((size_t)s * CIN + k) * 64 + n];
        ushortT hh = f2bf(wv);
        h[j] = hh;
        l[j] = f2bf(wv - bf2f(hh));
    }
    union { ushortT u[8]; uint4 v; } ph, pl;
#pragma unroll
    for (int j = 0; j < 8; j++) { ph.u[j] = h[j]; pl.u[j] = l[j]; }
    hi4[idx] = ph.v;
    lo4[idx] = pl.v;
}

// ---------------- Conv A (cin=1): one wave per 64-edge tile ----------
template<int C1>
__global__ void conv_a(const float* __restrict__ x, const int* __restrict__ ssrc,
                       const int* __restrict__ sdst,
                       const float* __restrict__ sfx, const float* __restrict__ sfy,
                       const float* __restrict__ sfz, const float* __restrict__ Wa,
                       const int* __restrict__ cellOfTile, const int* __restrict__ cs_pad,
                       const int* __restrict__ cellTot, float* __restrict__ f1) {
    int tile = blockIdx.x;
    int cell = cellOfTile[tile];
    if (cell < 0) return;
    int tb = tile * 64;
    int valid = cs_pad[cell] + cellTot[cell] - tb;
    valid = valid < 64 ? valid : 64;
    int lane = threadIdx.x;
    int cx = cell >> 4, cy = (cell >> 2) & 3, cz = cell & 3;
    float wv[8];
#pragma unroll
    for (int cor = 0; cor < 8; cor++) {
        int slot = (cx + (cor & 1)) * 25 + (cy + ((cor >> 1) & 1)) * 5 + (cz + ((cor >> 2) & 1));
        wv[cor] = (lane < C1) ? Wa[slot * C1 + lane] : 0.f;
    }
    for (int j = 0; j < valid; j++) {
        int e = tb + j;
        float fx = sfx[e], fy = sfy[e], fz = sfz[e];
        float gx = 1.f - fx, gy = 1.f - fy, gz = 1.f - fz;
        float p = 0.f;
#pragma unroll
        for (int cor = 0; cor < 8; cor++) {
            float wc = ((cor & 1) ? fx : gx) * (((cor >> 1) & 1) ? fy : gy) * (((cor >> 2) & 1) ? fz : gz);
            p = fmaf(wc, wv[cor], p);
        }
        float xs = x[rfl(ssrc[e])];
        int d = rfl(sdst[e]);
        if (lane < C1) atomicAdd(&f1[(size_t)d * C1 + lane], xs * p);
    }
}

// ---------------- Conv A epilogue: f1 = relu(f1/deg + x*root + bias) ----------------
template<int C1>
__global__ void node_a2(float* __restrict__ f1, const float* __restrict__ x,
                        const float* __restrict__ root, const float* __restrict__ bias,
                        const float* __restrict__ deg, int n) {
    int i = blockIdx.x * blockDim.x + threadIdx.x;
    if (i >= n * C1) return;
    int node = i / C1, ch = i - node * C1;
    float d = fmaxf(deg[node], 1.f);
    float o = f1[i] / d + x[node] * root[ch] + bias[ch];
    f1[i] = fmaxf(o, 0.f);
}

// ---------------- Conv B: MFMA per (cell,corner) GEMM, wc row-scale epilogue ----------
template<int CIN>
__launch_bounds__(256)
__global__ void conv_b_mfma(const float* __restrict__ f1, const int* __restrict__ ssrc,
                            const int* __restrict__ sdst,
                            const float* __restrict__ sfx, const float* __restrict__ sfy,
                            const float* __restrict__ sfz,
                            const uint4* __restrict__ whi, const uint4* __restrict__ wlo,
                            const int* __restrict__ cellOfTile, const int* __restrict__ cs_pad,
                            const int* __restrict__ cellTot, float* __restrict__ accb) {
    const int T = CIN / 32;
    const int SA = CIN + 8;          // padded LDS row stride (ushorts)
    int tile = blockIdx.x;
    int cell = cellOfTile[tile];
    if (cell < 0) return;
    int tb = tile * 64;
    int valid = cs_pad[cell] + cellTot[cell] - tb;
    valid = valid < 64 ? valid : 64;

    __shared__ alignas(16) ushortT Ahi[64 * (CIN + 8)];
    __shared__ alignas(16) ushortT Alo[64 * (CIN + 8)];
    __shared__ float fxs[64], fys[64], fzs[64];
    __shared__ int dsts[64];

    int t = threadIdx.x;
    if (t < 64) {
        bool v = t < valid;
        fxs[t] = v ? sfx[tb + t] : 0.f;
        fys[t] = v ? sfy[tb + t] : 0.f;
        fzs[t] = v ? sfz[tb + t] : 0.f;
        dsts[t] = v ? sdst[tb + t] : 0;
    }
    // A staging: edge = t>>2, seg = t&3 covers CIN/4 floats
    {
        const int FPT = CIN / 16;    // float4s per (edge,seg)
        int edge = t >> 2, seg = t & 3;
        ushortT* ah = &Ahi[edge * SA + seg * (CIN / 4)];
        ushortT* al = &Alo[edge * SA + seg * (CIN / 4)];
        if (edge < valid) {
            int src = ssrc[tb + edge];
            const float4* fp = (const float4*)(f1 + (size_t)src * CIN);
#pragma unroll
            for (int u = 0; u < FPT; u++) {
                float4 vv = fp[seg * FPT + u];
                float vals[4] = {vv.x, vv.y, vv.z, vv.w};
                ushort4 hh, ll;
                ushortT* hp = (ushortT*)&hh; ushortT* lp = (ushortT*)&ll;
#pragma unroll
                for (int c2 = 0; c2 < 4; c2++) {
                    ushortT h = f2bf(vals[c2]);
                    hp[c2] = h;
                    lp[c2] = f2bf(vals[c2] - bf2f(h));
                }
                *(ushort4*)(ah + u * 4) = hh;
                *(ushort4*)(al + u * 4) = ll;
            }
        } else {
            ushort4 z; ushortT* zp = (ushortT*)&z;
            zp[0] = zp[1] = zp[2] = zp[3] = 0;
#pragma unroll
            for (int u = 0; u < FPT; u++) {
                *(ushort4*)(ah + u * 4) = z;
                *(ushort4*)(al + u * 4) = z;
            }
        }
    }
    __syncthreads();

    int lane = t & 63, w = t >> 6;
    int q = lane >> 4, m = lane & 15;

    // A fragments for this wave's 16 edges (rows 16w+m), all K
    bf16x8 ah[T], al[T];
#pragma unroll
    for (int st = 0; st < T; st++) {
        ah[st] = *(const bf16x8*)&Ahi[(16 * w + m) * SA + st * 32 + q * 8];
        al[st] = *(const bf16x8*)&Alo[(16 * w + m) * SA + st * 32 + q * 8];
    }
    // per-lane row frac values (rows 16w + q*4 + r)
    float fxr[4], fyr[4], fzr[4], gxr[4], gyr[4], gzr[4];
#pragma unroll
    for (int r = 0; r < 4; r++) {
        int row = 16 * w + q * 4 + r;
        fxr[r] = fxs[row]; fyr[r] = fys[row]; fzr[r] = fzs[row];
        gxr[r] = 1.f - fxr[r]; gyr[r] = 1.f - fyr[r]; gzr[r] = 1.f - fzr[r];
    }

    int cx = cell >> 4, cy = (cell >> 2) & 3, cz = cell & 3;
    f32x4 acc[4];
#pragma unroll
    for (int b2 = 0; b2 < 4; b2++) acc[b2] = (f32x4){0.f, 0.f, 0.f, 0.f};

#pragma unroll
    for (int cor = 0; cor < 8; cor++) {
        const int bx = cor & 1, by = (cor >> 1) & 1, bz = (cor >> 2) & 1;
        int slot = (cx + bx) * 25 + (cy + by) * 5 + (cz + bz);
        f32x4 C[4];
#pragma unroll
        for (int b2 = 0; b2 < 4; b2++) C[b2] = (f32x4){0.f, 0.f, 0.f, 0.f};
#pragma unroll
        for (int st = 0; st < T; st++) {
            size_t fb = ((size_t)(slot * T + st) * 4) * 64 + lane;
            bf16x8 bh[4], bl[4];
#pragma unroll
            for (int b2 = 0; b2 < 4; b2++) {
                bh[b2] = __builtin_bit_cast(bf16x8, whi[fb + (size_t)b2 * 64]);
                bl[b2] = __builtin_bit_cast(bf16x8, wlo[fb + (size_t)b2 * 64]);
            }
#pragma unroll
            for (int b2 = 0; b2 < 4; b2++) {
                C[b2] = __builtin_amdgcn_mfma_f32_16x16x32_bf16(ah[st], bh[b2], C[b2], 0, 0, 0);
                C[b2] = __builtin_amdgcn_mfma_f32_16x16x32_bf16(al[st], bh[b2], C[b2], 0, 0, 0);
                C[b2] = __builtin_amdgcn_mfma_f32_16x16x32_bf16(ah[st], bl[b2], C[b2], 0, 0, 0);
            }
        }
        float wr[4];
#pragma unroll
        for (int r = 0; r < 4; r++)
            wr[r] = (bx ? fxr[r] : gxr[r]) * (by ? fyr[r] : gyr[r]) * (bz ? fzr[r] : gzr[r]);
#pragma unroll
        for (int b2 = 0; b2 < 4; b2++)
#pragma unroll
            for (int r = 0; r < 4; r++)
                acc[b2][r] = fmaf(wr[r], C[b2][r], acc[b2][r]);
    }

    // scatter: row = 16w + q*4 + r, col = m (+16*blk)
#pragma unroll
    for (int r = 0; r < 4; r++) {
        int row = 16 * w + q * 4 + r;
        if (row < valid) {
            int d = dsts[row];
            float* bp = &accb[(size_t)d * 64 + m];
            atomicAdd(bp + 0,  acc[0][r]);
            atomicAdd(bp + 16, acc[1][r]);
            atomicAdd(bp + 32, acc[2][r]);
            atomicAdd(bp + 48, acc[3][r]);
        }
    }
}

// ---------------- Conv B node epilogue + fused graph readout ----------------
template<int CIN>
__global__ void node_b(const float* __restrict__ accb, const float* __restrict__ f1,
                       const float* __restrict__ rootb, const float* __restrict__ biasb,
                       const float* __restrict__ deg, const int* __restrict__ batch,
                       float* __restrict__ hsum, float* __restrict__ gcnt, int lvloff) {
    __shared__ float sh[CIN];
    int node = blockIdx.x;
    int t = threadIdx.x;  // 64 threads
    if (t < CIN) sh[t] = f1[(size_t)node * CIN + t];
    __syncthreads();
    float s = accb[(size_t)node * 64 + t];
    float d = fmaxf(deg[node], 1.f);
    s /= d;
#pragma unroll
    for (int i = 0; i < CIN; i++) s = fmaf(sh[i], rootb[i * 64 + t], s);
    s += biasb[t];
    s = fmaxf(s, 0.f);
    int g = batch[node];
    atomicAdd(&hsum[g * 320 + lvloff + t], s);
    if (t == 0) atomicAdd(&gcnt[g], 1.0f);
}

// ---------------- FC + log_softmax ----------------
__global__ void fc_kernel(const float* __restrict__ hsum, const float* __restrict__ gcnt,
                          const float* __restrict__ fcw, const float* __restrict__ fcb,
                          float* __restrict__ out) {
    int g = threadIdx.x;
    if (g >= NUM_GRAPHS) return;
    float logit[10];
#pragma unroll
    for (int t = 0; t < 10; t++) logit[t] = fcb[t];
    for (int j = 0; j < 320; j++) {
        float c = fmaxf(gcnt[(j >> 6) * NUM_GRAPHS + g], 1.f);
        float h = hsum[g * 320 + j] / c;
#pragma unroll
        for (int t = 0; t < 10; t++) logit[t] = fmaf(h, fcw[j * 10 + t], logit[t]);
    }
    float m = logit[0];
#pragma unroll
    for (int t = 1; t < 10; t++) m = fmaxf(m, logit[t]);
    float sum = 0.f;
#pragma unroll
    for (int t = 0; t < 10; t++) sum += expf(logit[t] - m);
    float lse = m + logf(sum);
#pragma unroll
    for (int t = 0; t < 10; t++) out[g * 10 + t] = logit[t] - lse;
}

extern "C" void kernel_launch(void* const* d_in, const int* in_sizes, int n_in,
                              void* d_out, int out_size, void* d_ws, size_t ws_size,
                              hipStream_t stream) {
    static const int Ns[5] = {20000, 10000, 5000, 2500, 1250};
    static const int Es[5] = {320000, 160000, 80000, 40000, 20000};

    float* ws    = (float*)d_ws;
    float* deg   = ws;                                 // MAXN
    float* f1    = deg + MAXN;                         // MAXN*64
    float* accb  = f1 + (size_t)MAXN * 64;             // MAXN*64
    int*   ssrc  = (int*)(accb + (size_t)MAXN * 64);   // MAXE+4096
    int*   sdst  = ssrc + (MAXE + 4096);
    float* sfx   = (float*)(sdst + (MAXE + 4096));
    float* sfy   = sfx + (MAXE + 4096);
    float* sfz   = sfy + (MAXE + 4096);
    int*   bb    = (int*)(sfz + (MAXE + 4096));        // 1250*64
    int*   cs_pad   = bb + 1250 * 64;                  // 64
    int*   cellTot  = cs_pad + 64;                     // 64
    int*   cellOfTile = cellTot + 64;                  // MAXTILE1
    float* hsum  = (float*)(cellOfTile + MAXTILE1);    // 64*320
    float* gcnt  = hsum + NUM_GRAPHS * 320;            // 5*64
    uint4* whi   = (uint4*)(((size_t)(gcnt + 5 * NUM_GRAPHS) + 15) & ~(size_t)15);
    uint4* wlo   = whi + 125 * 2 * 4 * 64;             // 64000 uint4 each

    hipMemsetAsync(hsum, 0, (NUM_GRAPHS * 320 + 5 * NUM_GRAPHS) * sizeof(float), stream);

    for (int l = 0; l < 5; l++) {
        const int b = l * 10;
        const float* x      = (const float*)d_in[b + 0];
        const float* pseudo = (const float*)d_in[b + 1];
        const int*   ei     = (const int*)d_in[b + 2];
        const int*   batch  = (const int*)d_in[b + 3];
        const float* Wa     = (const float*)d_in[b + 4];
        const float* roota  = (const float*)d_in[b + 5];
        const float* biasa  = (const float*)d_in[b + 6];
        const float* Wb     = (const float*)d_in[b + 7];
        const float* rootb  = (const float*)d_in[b + 8];
        const float* biasb  = (const float*)d_in[b + 9];
        int n = Ns[l], e = Es[l];
        int c1 = (l == 0) ? 32 : 64;
        int maxTiles = e / 64 + 64;

        hipMemsetAsync(deg, 0, (MAXN + (size_t)n * c1) * sizeof(float), stream);
        hipMemsetAsync(accb, 0, (size_t)n * 64 * sizeof(float), stream);

        int nblkS = (e + 255) / 256;
        sort_hist<<<nblkS, 256, 0, stream>>>(pseudo, ei, e, bb, deg);
        sort_scan<<<1, 64, 0, stream>>>(bb, nblkS, cs_pad, cellTot, cellOfTile, maxTiles);
        sort_scatter<<<nblkS, 256, 0, stream>>>(pseudo, ei, e, bb, cs_pad,
                                                ssrc, sdst, sfx, sfy, sfz);

        if (l == 0) {
            wswz<32><<<(125 * 1 * 4 * 64 + 255) / 256, 256, 0, stream>>>(Wb, whi, wlo);
            conv_a<32><<<maxTiles, 64, 0, stream>>>(x, ssrc, sdst, sfx, sfy, sfz, Wa,
                                                    cellOfTile, cs_pad, cellTot, f1);
            node_a2<32><<<(n * 32 + 255) / 256, 256, 0, stream>>>(f1, x, roota, biasa, deg, n);
            conv_b_mfma<32><<<maxTiles, 256, 0, stream>>>(f1, ssrc, sdst, sfx, sfy, sfz,
                                                          whi, wlo, cellOfTile, cs_pad, cellTot, accb);
            node_b<32><<<n, 64, 0, stream>>>(accb, f1, rootb, biasb, deg, batch,
                                             hsum, gcnt + l * NUM_GRAPHS, l * 64);
        } else {
            wswz<64><<<(125 * 2 * 4 * 64 + 255) / 256, 256, 0, stream>>>(Wb, whi, wlo);
            conv_a<64><<<maxTiles, 64, 0, stream>>>(x, ssrc, sdst, sfx, sfy, sfz, Wa,
                                                    cellOfTile, cs_pad, cellTot, f1);
            node_a2<64><<<(n * 64 + 255) / 256, 256, 0, stream>>>(f1, x, roota, biasa, deg, n);
            conv_b_mfma<64><<<maxTiles, 256, 0, stream>>>(f1, ssrc, sdst, sfx, sfy, sfz,
                                                          whi, wlo, cellOfTile, cs_pad, cellTot, accb);
            node_b<64><<<n, 64, 0, stream>>>(accb, f1, rootb, biasb, deg, batch,
                                             hsum, gcnt + l * NUM_GRAPHS, l * 64);
        }
    }

    const float* fcw = (const float*)d_in[50];
    const float* fcb = (const float*)d_in[51];
    fc_kernel<<<1, 64, 0, stream>>>(hsum, gcnt, fcw, fcb, (float*)d_out);
}